// Round 2
// baseline (268.134 us; speedup 1.0000x reference)
//
#include <hip/hip_runtime.h>
#include <math.h>

#define NPIX 8192
#define KCB  4096
#define DH   32
#define DIN  192

// ---------------- kernel 2: codebook passthrough ----------------
__global__ void k_copy(const float* __restrict__ src, float* __restrict__ dst) {
  int i = blockIdx.x * 256 + threadIdx.x;
  dst[i] = src[i];  // grid sized exactly: 512*256 = 131072
}

// ---------------- kernel main: raw(f64) + logits(f64) + argmaxes + quantized ----------------
// grid 1024, block 256: 8 pixels/block; thread owns 4 codebook rows per 1024-chunk
__global__ __launch_bounds__(256) void k_main(
    const float* __restrict__ latent, const float* __restrict__ wv_w,
    const float* __restrict__ wv_b, const float* __restrict__ cb,
    const float* __restrict__ gumbel, const float* __restrict__ temp1p,
    const int* __restrict__ tempp,
    float* __restrict__ raw_out, float* __restrict__ logit_out,
    float* __restrict__ code_out, float* __restrict__ true_out,
    float* __restrict__ quant_out) {
  __shared__ float  wv[DH * 193];          // 24.7 KB, padded stride: conflict-free
  __shared__ double raw_s[8][DH];          // 2 KB
  __shared__ double x2_s[8];
  __shared__ double redv[2][8][4];
  __shared__ int    redi[2][8][4];
  __shared__ int    code_s[8];

  const int tid  = threadIdx.x;
  const int pix0 = blockIdx.x * 8;

  // ---- stage wv_w (fp32) ----
  for (int idx = tid; idx < DH * DIN; idx += 256) {
    int o = idx / DIN, i = idx - o * DIN;
    wv[o * 193 + i] = wv_w[idx];
  }
  __syncthreads();

  // ---- raw in f64 (matches f64 reference; also emit fp32 raw output) ----
  {
    const int p = tid >> 5, o = tid & 31;
    const int gpix = pix0 + p;
    const int b = gpix >> 10, hw = gpix & 1023;
    const float* lp = latent + b * (DIN * 1024) + hw;  // stride 1024 over channel
    double acc = (double)wv_b[o];
    #pragma unroll 4
    for (int i = 0; i < DIN; ++i)
      acc = fma((double)lp[i * 1024], (double)wv[o * 193 + i], acc);
    raw_s[p][o] = acc;
    raw_out[gpix * DH + o] = (float)acc;
  }
  __syncthreads();
  if (tid < 8) {
    double s = 0.0;
    #pragma unroll
    for (int d = 0; d < DH; ++d) s = fma(raw_s[tid][d], raw_s[tid][d], s);
    x2_s[tid] = s;
  }
  __syncthreads();

  const double t   = (double)(*tempp);
  const double tt  = (double)(*temp1p) * t;
  const double tau = sqrt(t);

  double x2r[8];
  #pragma unroll
  for (int p = 0; p < 8; ++p) x2r[p] = x2_s[p];

  double bl[8], bg[8];
  int    bli[8], bgi[8];
  #pragma unroll
  for (int p = 0; p < 8; ++p) { bl[p] = -INFINITY; bg[p] = -INFINITY; bli[p] = 0; bgi[p] = 0; }

  // ---- main loop: 4 chunks of 1024 k; thread rows k = c*1024 + j*256 + tid ----
  #pragma unroll 1
  for (int c = 0; c < 4; ++c) {
    const int kbase = c * 1024 + tid;
    double dots[8][4];
    double c2[4];
    #pragma unroll
    for (int p = 0; p < 8; ++p)
      #pragma unroll
      for (int j = 0; j < 4; ++j) dots[p][j] = 0.0;
    #pragma unroll
    for (int j = 0; j < 4; ++j) c2[j] = 0.0;

    #pragma unroll 2
    for (int db = 0; db < 8; ++db) {     // d-blocks of 4
      float4 rf[4];
      #pragma unroll
      for (int j = 0; j < 4; ++j)
        rf[j] = *(const float4*)(cb + (kbase + j * 256) * DH + db * 4);
      double rd[4][4];
      #pragma unroll
      for (int j = 0; j < 4; ++j) {
        rd[j][0] = (double)rf[j].x; rd[j][1] = (double)rf[j].y;
        rd[j][2] = (double)rf[j].z; rd[j][3] = (double)rf[j].w;
        #pragma unroll
        for (int e = 0; e < 4; ++e) c2[j] = fma(rd[j][e], rd[j][e], c2[j]);
      }
      #pragma unroll
      for (int p = 0; p < 8; ++p) {
        double2 ra = *(const double2*)&raw_s[p][db * 4];
        double2 rb = *(const double2*)&raw_s[p][db * 4 + 2];
        #pragma unroll
        for (int j = 0; j < 4; ++j) {
          dots[p][j] = fma(rd[j][0], ra.x, dots[p][j]);
          dots[p][j] = fma(rd[j][1], ra.y, dots[p][j]);
          dots[p][j] = fma(rd[j][2], rb.x, dots[p][j]);
          dots[p][j] = fma(rd[j][3], rb.y, dots[p][j]);
        }
      }
    }

    // logit write + argmax tracking (k ascends with (c,j): strict > = first occurrence)
    #pragma unroll
    for (int p = 0; p < 8; ++p) {
      const int rowbase = (pix0 + p) * KCB;
      #pragma unroll
      for (int j = 0; j < 4; ++j) {
        const int k = kbase + j * 256;
        double lraw = -((x2r[p] + c2[j]) - 2.0 * dots[p][j]);
        logit_out[rowbase + k] = (float)lraw;
        double zt = lraw / tt;
        if (zt > bl[p]) { bl[p] = zt; bli[p] = k; }
        double zg = (zt + (double)gumbel[rowbase + k]) / tau;
        if (zg > bg[p]) { bg[p] = zg; bgi[p] = k; }
      }
    }
  }

  // ---- block argmax reduction: 64-lane butterfly (val,idx), then 4 waves via LDS ----
  const int wave = tid >> 6, lane = tid & 63;
  #pragma unroll
  for (int p = 0; p < 8; ++p) {
    double vl = bl[p], vg = bg[p];
    int    il = bli[p], ig = bgi[p];
    #pragma unroll
    for (int m = 32; m; m >>= 1) {
      double ov = __shfl_xor(vl, m, 64); int oi = __shfl_xor(il, m, 64);
      if (ov > vl || (ov == vl && oi < il)) { vl = ov; il = oi; }
      double og = __shfl_xor(vg, m, 64); int og_i = __shfl_xor(ig, m, 64);
      if (og > vg || (og == vg && og_i < ig)) { vg = og; ig = og_i; }
    }
    if (lane == 0) {
      redv[0][p][wave] = vl; redi[0][p][wave] = il;
      redv[1][p][wave] = vg; redi[1][p][wave] = ig;
    }
  }
  __syncthreads();
  if (tid < 8) {
    const int p = tid;
    double vl = redv[0][p][0], vg = redv[1][p][0];
    int    il = redi[0][p][0], ig = redi[1][p][0];
    #pragma unroll
    for (int w2 = 1; w2 < 4; ++w2) {
      double ov = redv[0][p][w2]; int oi = redi[0][p][w2];
      if (ov > vl || (ov == vl && oi < il)) { vl = ov; il = oi; }
      double og = redv[1][p][w2]; int oj = redi[1][p][w2];
      if (og > vg || (og == vg && oj < ig)) { vg = og; ig = oj; }
    }
    true_out[pix0 + p] = (float)il;
    code_out[pix0 + p] = (float)ig;
    code_s[p] = ig;
  }
  __syncthreads();
  // quantized = codebook[code] (f64 sample is one-hot to ~1e-16; rounds back to cb fp32)
  quant_out[pix0 * DH + tid] = cb[code_s[tid >> 5] * DH + (tid & 31)];
}

// ---------------- kernel 4: hard = quantized @ wq_w^T + wq_b, NCHW out ----------------
__global__ __launch_bounds__(256) void k_hard(const float* __restrict__ quant,
    const float* __restrict__ wq_w, const float* __restrict__ wq_b,
    float* __restrict__ hard) {
  __shared__ float wq[DIN * DH];   // 24KB, broadcast reads
  __shared__ float qs[32][33];     // padded
  const int bh = blockIdx.x;       // b*32 + h
  const int b = bh >> 5, h = bh & 31;
  for (int idx = threadIdx.x; idx < DIN * DH; idx += 256) wq[idx] = wq_w[idx];
  for (int idx = threadIdx.x; idx < 32 * DH; idx += 256)
    qs[idx >> 5][idx & 31] = quant[bh * (32 * DH) + idx];
  __syncthreads();
  for (int it = 0; it < (DIN * 32) / 256; ++it) {
    const int idx = it * 256 + threadIdx.x;
    const int o = idx >> 5, w = idx & 31;
    float acc = wq_b[o];
    #pragma unroll
    for (int d = 0; d < DH; ++d) acc = fmaf(qs[w][d], wq[o * DH + d], acc);
    hard[((b * DIN + o) * 32 + h) * 32 + w] = acc;
  }
}

extern "C" void kernel_launch(void* const* d_in, const int* in_sizes, int n_in,
                              void* d_out, int out_size, void* d_ws, size_t ws_size,
                              hipStream_t stream) {
  const float* latent      = (const float*)d_in[0];
  const float* cb          = (const float*)d_in[1];
  const float* wv_w        = (const float*)d_in[2];
  const float* wv_b        = (const float*)d_in[3];
  const float* wq_w        = (const float*)d_in[4];
  const float* wq_b        = (const float*)d_in[5];
  const float* temp1       = (const float*)d_in[6];
  const float* gumbel      = (const float*)d_in[7];
  const int*   temperature = (const int*)d_in[8];

  float* out      = (float*)d_out;
  float* hard     = out;                 // 8*192*32*32   = 1572864
  float* code     = out + 1572864;       // 8192
  float* true_c   = out + 1581056;       // 8192
  float* logitRaw = out + 1589248;       // 33554432
  float* raw      = out + 35143680;      // 262144
  float* quant    = out + 35405824;      // 262144
  float* cb_out   = out + 35668096;      // 131072

  k_copy<<<(KCB * DH) / 256, 256, 0, stream>>>(cb, cb_out);
  k_main<<<NPIX / 8, 256, 0, stream>>>(latent, wv_w, wv_b, cb, gumbel, temp1,
                                       temperature, raw, logitRaw, code, true_c, quant);
  k_hard<<<8 * 32, 256, 0, stream>>>(quant, wq_w, wq_b, hard);
}